// Round 1
// baseline (141.160 us; speedup 1.0000x reference)
//
#include <hip/hip_runtime.h>

typedef _Float16 f16;
typedef f16 f16x4 __attribute__((ext_vector_type(4)));
typedef f16 f16x8 __attribute__((ext_vector_type(8)));
typedef float f32x4 __attribute__((ext_vector_type(4)));

// state_embed (256,512) f32 | action_feats (256,1000,64) f32 | W1 (576,256) | b1 (256)
// W2 (256,128) | b2 (128) | W3 (128,1) | b3 (1)  -> out (256,1000) f32

#define AF_STRIDE 72    // 64+8 f16 = 36 dwords/row
#define H1_STRIDE 264   // 256+8 f16 = 132 dwords/row

// ---------- prep: pack W1a^T (A-frag), W2 (B-frag), compute h_state ----------
// A-frag (16x16x32): lane L holds A[m=L&15][k=(L>>4)*8+j], j=0..7
// B-frag:            lane L holds B[k=(L>>4)*8+j][n=L&15]
__global__ __launch_bounds__(256) void prep_kernel(const float* __restrict__ W1,
                                                   const float* __restrict__ W2,
                                                   const float* __restrict__ state,
                                                   const float* __restrict__ b1,
                                                   f16* __restrict__ pw1at,
                                                   f16* __restrict__ pw2,
                                                   float* __restrict__ hstate) {
    __shared__ float srow[512];
    int blk = blockIdx.x;
    int tid = threadIdx.x;
    if (blk < 24) {
        int idx = blk * 256 + tid;              // 0..6143
        int F = idx >> 6;                       // fragment id 0..95
        int L = idx & 63;
        int q = L >> 4, c = L & 15;
        f16x8 v;
        if (F < 32) {                           // pw1at: M=256h (mt 0..15), K=64f (kt 0..1)
            int mt = F >> 1, kt = F & 1;
            #pragma unroll
            for (int j = 0; j < 8; ++j) {
                int f = kt * 32 + q * 8 + j;
                v[j] = (f16)W1[(size_t)(512 + f) * 256 + mt * 16 + c];
            }
            *(f16x8*)(pw1at + ((size_t)F * 64 + L) * 8) = v;
        } else {                                // pw2: K=256 (kt 0..7), N=128 (nt 0..7)
            int F2 = F - 32;
            int nt = F2 >> 3, kt = F2 & 7;
            #pragma unroll
            for (int j = 0; j < 8; ++j) {
                int k = kt * 32 + q * 8 + j;
                v[j] = (f16)W2[(size_t)k * 128 + nt * 16 + c];
            }
            *(f16x8*)(pw2 + ((size_t)F2 * 64 + L) * 8) = v;
        }
    } else {
        int b = blk - 24;                       // one batch row per block (fp32 exact)
        srow[tid] = state[(size_t)b * 512 + tid];
        srow[tid + 256] = state[(size_t)b * 512 + 256 + tid];
        __syncthreads();
        float a0 = 0.f, a1 = 0.f;
        #pragma unroll 8
        for (int f = 0; f < 512; f += 2) {
            a0 = fmaf(srow[f],     W1[(size_t)f * 256 + tid],       a0);
            a1 = fmaf(srow[f + 1], W1[(size_t)(f + 1) * 256 + tid], a1);
        }
        hstate[(size_t)b * 256 + tid] = a0 + a1 + b1[tid];
    }
}

// ---------- fused MLP: 2 tiles x 64 actions/block, h-split waves ----------
// Register history: R6 resident-everything = ~208 regs -> 2 waves/SIMD, 43.2us.
// R5/R7: capping to 3 waves (launch_bounds .,3) spills (WRITE_SIZE 95/30 MB).
// R8 (prev): low-pressure body landed 104 VGPR but LDS 55296 B > 54613 B kept HW at
//   2 blocks/CU (the "53.76KB" comment miscounted lds3) -> Occupancy 17%, MfmaUtil 20%.
// This round: alias lds3[2][384] into afs2 tile-0 bytes [0,3072) (dead after tile-0
// bf loads; every hazard pair barrier-separated) -> LDS 52224 B, 3x52224 <= 163840
// -> 3 blocks/CU, 3 waves/SIMD. VGPR 104 <= 170 so regalloc is not the limiter.
__global__ __launch_bounds__(256, 2) void fused_kernel(const float* __restrict__ afeat,
                                                       const float* __restrict__ hstate,
                                                       const f16* __restrict__ pw1at,
                                                       const f16* __restrict__ pw2,
                                                       const float* __restrict__ b2,
                                                       const float* __restrict__ W3,
                                                       const float* __restrict__ b3,
                                                       float* __restrict__ out) {
    // 52224 B total: afs2 18432 B | h1s 33792 B ; lds3 (2x1536 B) aliases afs2[0:3072)
    __shared__ __align__(16) char smem[(128 * AF_STRIDE + 64 * H1_STRIDE) * 2];
    f16* afs2 = (f16*)smem;                                // 2 tiles of action_feats (f16)
    f16* h1s  = (f16*)(smem + 128 * AF_STRIDE * 2);
    float* lds3 = (float*)smem;                            // [t*384 + m*6 + w]
    // liveness: lds3[t] written after B1(t), read after B2(t). afs2 bytes [0,3072)
    // (tile-0 rows 0..21) are only read by tile-0 bf loads, which all precede B1(0).
    // All conflicting accesses are separated by __syncthreads -> no race, no reorder.

    int tid = threadIdx.x;
    int w = tid >> 6;                 // wave 0..3
    int L = tid & 63;
    int q = L >> 4, c = L & 15;
    int r0g = blockIdx.x * 128;       // first global action row of this block's 2 tiles

    // ---- resident W1a^T A-frags (32 VGPRs), wave's h-slice [64w, 64w+64) ----
    f16x8 a1f[4][2];
    #pragma unroll
    for (int i = 0; i < 4; ++i)
        #pragma unroll
        for (int kt = 0; kt < 2; ++kt)
            a1f[i][kt] = *(const f16x8*)(pw1at + ((size_t)((4 * w + i) * 2 + kt) * 64 + L) * 8);

    // ---- stage both tiles: 128 rows x 64 f32 -> f16 LDS ----
    #pragma unroll
    for (int i = 0; i < 4; ++i) {
        int id = i * 256 + tid;               // 32B-chunk id 0..1023
        int row = id >> 3, c32 = id & 7;
        const float* p = afeat + (size_t)(r0g + row) * 64 + c32 * 8;
        f32x4 lo = *(const f32x4*)p;
        f32x4 hi = *(const f32x4*)(p + 4);
        f16x8 v;
        v[0] = (f16)lo[0]; v[1] = (f16)lo[1]; v[2] = (f16)lo[2]; v[3] = (f16)lo[3];
        v[4] = (f16)hi[0]; v[5] = (f16)hi[1]; v[6] = (f16)hi[2]; v[7] = (f16)hi[3];
        *(f16x8*)(afs2 + row * AF_STRIDE + c32 * 8) = v;
    }

    float b3v = b3[0];
    float b2v[2], w3v[2];
    #pragma unroll
    for (int ntl = 0; ntl < 2; ++ntl) {
        int col = (w * 2 + ntl) * 16 + c;
        b2v[ntl] = b2[col];
        w3v[ntl] = W3[col];
    }
    __syncthreads();

    for (int t = 0; t < 2; ++t) {
        int r0 = r0g + t * 64;
        int b0i = r0 / 1000;
        int boundary = (b0i + 1) * 1000;
        int b1i = b0i < 255 ? b0i + 1 : 255;

        // ---- GEMM1 B-frags (shared across i-slices) ----
        f16x8 bf[4][2];
        #pragma unroll
        for (int nt = 0; nt < 4; ++nt)
            #pragma unroll
            for (int kt = 0; kt < 2; ++kt)
                bf[nt][kt] = *(const f16x8*)(afs2 + (t * 64 + nt * 16 + c) * AF_STRIDE + kt * 32 + q * 8);

        // ---- GEMM1 interleaved with epilogue-1: acc live = 16 regs per i-slice ----
        #pragma unroll
        for (int i = 0; i < 4; ++i) {
            f32x4 acc[4];
            #pragma unroll
            for (int nt = 0; nt < 4; ++nt) {
                acc[nt] = (f32x4){0.f, 0.f, 0.f, 0.f};
                #pragma unroll
                for (int kt = 0; kt < 2; ++kt)
                    acc[nt] = __builtin_amdgcn_mfma_f32_16x16x32_f16(
                        a1f[i][kt], bf[nt][kt], acc[nt], 0, 0, 0);
            }
            int hbase = (4 * w + i) * 16 + q * 4;
            f32x4 hsA = *(const f32x4*)(hstate + (size_t)b0i * 256 + hbase);
            f32x4 hsB = *(const f32x4*)(hstate + (size_t)b1i * 256 + hbase);
            #pragma unroll
            for (int nt = 0; nt < 4; ++nt) {
                bool sel = (r0 + nt * 16 + c) >= boundary;
                f16x4 hv;
                #pragma unroll
                for (int reg = 0; reg < 4; ++reg) {
                    float v = acc[nt][reg] + (sel ? hsB[reg] : hsA[reg]);
                    v = v > 0.f ? v : 0.f;
                    hv[reg] = (f16)v;
                }
                *(f16x4*)(h1s + (nt * 16 + c) * H1_STRIDE + hbase) = hv;
            }
        }
        __syncthreads();   // B1: h1s ready (and afs2 tile-0 reads all done -> lds3[t] writable)

        // ---- GEMM2: h2(64x128) = h1 @ W2; wave w owns n-slice [32w, 32w+32);
        //      W2 B-frags streamed from L2 each kt (16 KB/wave/tile) ----
        f32x4 acc2[4][2];
        #pragma unroll
        for (int rb = 0; rb < 4; ++rb) {
            acc2[rb][0] = (f32x4){0.f, 0.f, 0.f, 0.f};
            acc2[rb][1] = (f32x4){0.f, 0.f, 0.f, 0.f};
        }
        #pragma unroll
        for (int kt = 0; kt < 8; ++kt) {
            f16x8 a2[4];
            #pragma unroll
            for (int rb = 0; rb < 4; ++rb)
                a2[rb] = *(const f16x8*)(h1s + (rb * 16 + c) * H1_STRIDE + kt * 32 + q * 8);
            #pragma unroll
            for (int ntl = 0; ntl < 2; ++ntl) {
                f16x8 bfr = *(const f16x8*)(pw2 + ((size_t)((w * 2 + ntl) * 8 + kt) * 64 + L) * 8);
                #pragma unroll
                for (int rb = 0; rb < 4; ++rb)
                    acc2[rb][ntl] = __builtin_amdgcn_mfma_f32_16x16x32_f16(
                        a2[rb], bfr, acc2[rb][ntl], 0, 0, 0);
            }
        }

        // ---- layer 3: partial over wave's n-slice; butterfly-reduce over 16 c-lanes ----
        float p[16];
        #pragma unroll
        for (int rb = 0; rb < 4; ++rb)
            #pragma unroll
            for (int reg = 0; reg < 4; ++reg) {
                float v0 = acc2[rb][0][reg] + b2v[0]; v0 = v0 > 0.f ? v0 : 0.f;
                float v1 = acc2[rb][1][reg] + b2v[1]; v1 = v1 > 0.f ? v1 : 0.f;
                p[rb * 4 + reg] = fmaf(v0, w3v[0], v1 * w3v[1]);
            }
        float s0[8];
        #pragma unroll
        for (int i = 0; i < 8; ++i) {
            float send = (c & 1) ? p[2 * i] : p[2 * i + 1];
            float keep = (c & 1) ? p[2 * i + 1] : p[2 * i];
            s0[i] = keep + __shfl_xor(send, 1);
        }
        float s1[4];
        #pragma unroll
        for (int i = 0; i < 4; ++i) {
            float send = (c & 2) ? s0[2 * i] : s0[2 * i + 1];
            float keep = (c & 2) ? s0[2 * i + 1] : s0[2 * i];
            s1[i] = keep + __shfl_xor(send, 2);
        }
        float s2[2];
        #pragma unroll
        for (int i = 0; i < 2; ++i) {
            float send = (c & 4) ? s1[2 * i] : s1[2 * i + 1];
            float keep = (c & 4) ? s1[2 * i + 1] : s1[2 * i];
            s2[i] = keep + __shfl_xor(send, 4);
        }
        float send3 = (c & 8) ? s2[0] : s2[1];
        float keep3 = (c & 8) ? s2[1] : s2[0];
        float s3 = keep3 + __shfl_xor(send3, 8);    // full c-sum for j=c
        int m = (c >> 2) * 16 + q * 4 + (c & 3);
        lds3[t * 384 + m * 6 + w] = s3;
        __syncthreads();   // B2: lds3[t] ready, h1s reads done (t=1 GEMM1 may overwrite)

        if (tid < 64) {
            const float* pm = lds3 + t * 384 + tid * 6;
            out[r0 + tid] = pm[0] + pm[1] + pm[2] + pm[3] + b3v;
        }
        // no B3: next tile writes lds3[t^1] region and h1s (already synced at B2)
    }
}

extern "C" void kernel_launch(void* const* d_in, const int* in_sizes, int n_in,
                              void* d_out, int out_size, void* d_ws, size_t ws_size,
                              hipStream_t stream) {
    const float* state = (const float*)d_in[0];
    const float* afeat = (const float*)d_in[1];
    const float* W1    = (const float*)d_in[2];
    const float* b1    = (const float*)d_in[3];
    const float* W2    = (const float*)d_in[4];
    const float* b2    = (const float*)d_in[5];
    const float* W3    = (const float*)d_in[6];
    const float* b3    = (const float*)d_in[7];
    float* out = (float*)d_out;

    // ws: hstate 256KB | pw1at 32KB (16384 f16) | pw2 64KB (32768 f16)
    float* hstate = (float*)d_ws;
    f16* pw1at = (f16*)((char*)d_ws + 65536 * sizeof(float));
    f16* pw2   = pw1at + 16384;

    prep_kernel<<<280, 256, 0, stream>>>(W1, W2, state, b1, pw1at, pw2, hstate);
    fused_kernel<<<2000, 256, 0, stream>>>(afeat, hstate, pw1at, pw2, b2, W3, b3, out);
}

// Round 2
// 137.022 us; speedup vs baseline: 1.0302x; 1.0302x over previous
//
#include <hip/hip_runtime.h>

typedef _Float16 f16;
typedef f16 f16x4 __attribute__((ext_vector_type(4)));
typedef f16 f16x8 __attribute__((ext_vector_type(8)));
typedef float f32x4 __attribute__((ext_vector_type(4)));

// state_embed (256,512) f32 | action_feats (256,1000,64) f32 | W1 (576,256) | b1 (256)
// W2 (256,128) | b2 (128) | W3 (128,1) | b3 (1)  -> out (256,1000) f32

#define AF_STRIDE 64    // unpadded; XOR swizzle supplies the bank rotation
#define H1_STRIDE 256   // unpadded; XOR swizzle supplies the bank rotation

// ---------- prep: pack W1a^T (A-frag), W2 (B-frag), compute h_state ----------
// A-frag (16x16x32): lane L holds A[m=L&15][k=(L>>4)*8+j], j=0..7
// B-frag:            lane L holds B[k=(L>>4)*8+j][n=L&15]
__global__ __launch_bounds__(256) void prep_kernel(const float* __restrict__ W1,
                                                   const float* __restrict__ W2,
                                                   const float* __restrict__ state,
                                                   const float* __restrict__ b1,
                                                   f16* __restrict__ pw1at,
                                                   f16* __restrict__ pw2,
                                                   float* __restrict__ hstate) {
    __shared__ float srow[512];
    int blk = blockIdx.x;
    int tid = threadIdx.x;
    if (blk < 24) {
        int idx = blk * 256 + tid;              // 0..6143
        int F = idx >> 6;                       // fragment id 0..95
        int L = idx & 63;
        int q = L >> 4, c = L & 15;
        f16x8 v;
        if (F < 32) {                           // pw1at: M=256h (mt 0..15), K=64f (kt 0..1)
            int mt = F >> 1, kt = F & 1;
            #pragma unroll
            for (int j = 0; j < 8; ++j) {
                int f = kt * 32 + q * 8 + j;
                v[j] = (f16)W1[(size_t)(512 + f) * 256 + mt * 16 + c];
            }
            *(f16x8*)(pw1at + ((size_t)F * 64 + L) * 8) = v;
        } else {                                // pw2: K=256 (kt 0..7), N=128 (nt 0..7)
            int F2 = F - 32;
            int nt = F2 >> 3, kt = F2 & 7;
            #pragma unroll
            for (int j = 0; j < 8; ++j) {
                int k = kt * 32 + q * 8 + j;
                v[j] = (f16)W2[(size_t)k * 128 + nt * 16 + c];
            }
            *(f16x8*)(pw2 + ((size_t)F2 * 64 + L) * 8) = v;
        }
    } else {
        int b = blk - 24;                       // one batch row per block (fp32 exact)
        srow[tid] = state[(size_t)b * 512 + tid];
        srow[tid + 256] = state[(size_t)b * 512 + 256 + tid];
        __syncthreads();
        float a0 = 0.f, a1 = 0.f;
        #pragma unroll 8
        for (int f = 0; f < 512; f += 2) {
            a0 = fmaf(srow[f],     W1[(size_t)f * 256 + tid],       a0);
            a1 = fmaf(srow[f + 1], W1[(size_t)(f + 1) * 256 + tid], a1);
        }
        hstate[(size_t)b * 256 + tid] = a0 + a1 + b1[tid];
    }
}

// ---------- fused MLP: 1 tile x 64 actions/block, h-split waves ----------
// History: R8 2-tile/52224B -> 3 blk/CU, fused 42us, MfmaUtil 22, Occ 17 — latency-bound.
// R9 (this): 1 tile/block, 4000 blocks. LDS = afs 8192 + h1s 32768 = 40960 B exactly
//   -> 4 blk/CU (4x40960 == 163840). Pads removed (they provided an additive 16*(row&7)
//   bank rotation); replaced by T2 XOR swizzle (off ^= (row&7)<<3 f16-units, 16B gran)
//   applied identically on write and read. lds3 aliases afs bytes [0,1536) — afs reads
//   (bf frags) all precede B1; lds3 writes all follow B1. launch_bounds (256,4) pins
//   VGPR <= 128 so regalloc can't forfeit the 4th block (current body ~104 VGPR).
__global__ __launch_bounds__(256, 4) void fused_kernel(const float* __restrict__ afeat,
                                                       const float* __restrict__ hstate,
                                                       const f16* __restrict__ pw1at,
                                                       const f16* __restrict__ pw2,
                                                       const float* __restrict__ b2,
                                                       const float* __restrict__ W3,
                                                       const float* __restrict__ b3,
                                                       float* __restrict__ out) {
    __shared__ __align__(16) char smem[(64 * AF_STRIDE + 64 * H1_STRIDE) * 2];  // 40960 B
    f16* afs = (f16*)smem;                                 // 64 rows x 64 f16, swizzled
    f16* h1s = (f16*)(smem + 64 * AF_STRIDE * 2);          // 64 rows x 256 f16, swizzled
    float* lds3 = (float*)smem;                            // aliases afs rows 0..11

    int tid = threadIdx.x;
    int w = tid >> 6;                 // wave 0..3
    int L = tid & 63;
    int q = L >> 4, c = L & 15;
    int r0 = blockIdx.x * 64;         // first global action row of this block's tile

    // ---- resident W1a^T A-frags (32 VGPRs), wave's h-slice [64w, 64w+64) ----
    f16x8 a1f[4][2];
    #pragma unroll
    for (int i = 0; i < 4; ++i)
        #pragma unroll
        for (int kt = 0; kt < 2; ++kt)
            a1f[i][kt] = *(const f16x8*)(pw1at + ((size_t)((4 * w + i) * 2 + kt) * 64 + L) * 8);

    // ---- stage tile: 64 rows x 64 f32 -> f16 LDS (swizzled) ----
    #pragma unroll
    for (int i = 0; i < 2; ++i) {
        int id = i * 256 + tid;               // 32B-chunk id 0..511
        int row = id >> 3, c32 = id & 7;
        const float* p = afeat + (size_t)(r0 + row) * 64 + c32 * 8;
        f32x4 lo = *(const f32x4*)p;
        f32x4 hi = *(const f32x4*)(p + 4);
        f16x8 v;
        v[0] = (f16)lo[0]; v[1] = (f16)lo[1]; v[2] = (f16)lo[2]; v[3] = (f16)lo[3];
        v[4] = (f16)hi[0]; v[5] = (f16)hi[1]; v[6] = (f16)hi[2]; v[7] = (f16)hi[3];
        *(f16x8*)(afs + row * AF_STRIDE + ((c32 * 8) ^ ((row & 7) << 3))) = v;
    }

    float b3v = b3[0];
    float b2v[2], w3v[2];
    #pragma unroll
    for (int ntl = 0; ntl < 2; ++ntl) {
        int col = (w * 2 + ntl) * 16 + c;
        b2v[ntl] = b2[col];
        w3v[ntl] = W3[col];
    }
    __syncthreads();

    int b0i = r0 / 1000;
    int boundary = (b0i + 1) * 1000;
    int b1i = b0i < 255 ? b0i + 1 : 255;
    int sx = (c & 7) << 3;            // lane's row-class XOR (rows used below are X*16+c)

    // ---- GEMM1 B-frags (shared across i-slices) ----
    f16x8 bf[4][2];
    #pragma unroll
    for (int nt = 0; nt < 4; ++nt)
        #pragma unroll
        for (int kt = 0; kt < 2; ++kt)
            bf[nt][kt] = *(const f16x8*)(afs + (nt * 16 + c) * AF_STRIDE + ((kt * 32 + q * 8) ^ sx));

    // ---- GEMM1 interleaved with epilogue-1: acc live = 16 regs per i-slice ----
    #pragma unroll
    for (int i = 0; i < 4; ++i) {
        f32x4 acc[4];
        #pragma unroll
        for (int nt = 0; nt < 4; ++nt) {
            acc[nt] = (f32x4){0.f, 0.f, 0.f, 0.f};
            #pragma unroll
            for (int kt = 0; kt < 2; ++kt)
                acc[nt] = __builtin_amdgcn_mfma_f32_16x16x32_f16(
                    a1f[i][kt], bf[nt][kt], acc[nt], 0, 0, 0);
        }
        int hbase = (4 * w + i) * 16 + q * 4;
        f32x4 hsA = *(const f32x4*)(hstate + (size_t)b0i * 256 + hbase);
        f32x4 hsB = *(const f32x4*)(hstate + (size_t)b1i * 256 + hbase);
        #pragma unroll
        for (int nt = 0; nt < 4; ++nt) {
            bool sel = (r0 + nt * 16 + c) >= boundary;
            f16x4 hv;
            #pragma unroll
            for (int reg = 0; reg < 4; ++reg) {
                float v = acc[nt][reg] + (sel ? hsB[reg] : hsA[reg]);
                v = v > 0.f ? v : 0.f;
                hv[reg] = (f16)v;
            }
            *(f16x4*)(h1s + (nt * 16 + c) * H1_STRIDE + (hbase ^ sx)) = hv;
        }
    }
    __syncthreads();   // B1: h1s ready; afs reads done -> lds3 region writable

    // ---- GEMM2: h2(64x128) = h1 @ W2; wave w owns n-slice [32w, 32w+32);
    //      W2 B-frags streamed from L2 each kt (16 KB/wave) ----
    f32x4 acc2[4][2];
    #pragma unroll
    for (int rb = 0; rb < 4; ++rb) {
        acc2[rb][0] = (f32x4){0.f, 0.f, 0.f, 0.f};
        acc2[rb][1] = (f32x4){0.f, 0.f, 0.f, 0.f};
    }
    #pragma unroll
    for (int kt = 0; kt < 8; ++kt) {
        f16x8 a2[4];
        #pragma unroll
        for (int rb = 0; rb < 4; ++rb)
            a2[rb] = *(const f16x8*)(h1s + (rb * 16 + c) * H1_STRIDE + ((kt * 32 + q * 8) ^ sx));
        #pragma unroll
        for (int ntl = 0; ntl < 2; ++ntl) {
            f16x8 bfr = *(const f16x8*)(pw2 + ((size_t)((w * 2 + ntl) * 8 + kt) * 64 + L) * 8);
            #pragma unroll
            for (int rb = 0; rb < 4; ++rb)
                acc2[rb][ntl] = __builtin_amdgcn_mfma_f32_16x16x32_f16(
                    a2[rb], bfr, acc2[rb][ntl], 0, 0, 0);
        }
    }

    // ---- layer 3: partial over wave's n-slice; butterfly-reduce over 16 c-lanes ----
    float p[16];
    #pragma unroll
    for (int rb = 0; rb < 4; ++rb)
        #pragma unroll
        for (int reg = 0; reg < 4; ++reg) {
            float v0 = acc2[rb][0][reg] + b2v[0]; v0 = v0 > 0.f ? v0 : 0.f;
            float v1 = acc2[rb][1][reg] + b2v[1]; v1 = v1 > 0.f ? v1 : 0.f;
            p[rb * 4 + reg] = fmaf(v0, w3v[0], v1 * w3v[1]);
        }
    float s0[8];
    #pragma unroll
    for (int i = 0; i < 8; ++i) {
        float send = (c & 1) ? p[2 * i] : p[2 * i + 1];
        float keep = (c & 1) ? p[2 * i + 1] : p[2 * i];
        s0[i] = keep + __shfl_xor(send, 1);
    }
    float s1[4];
    #pragma unroll
    for (int i = 0; i < 4; ++i) {
        float send = (c & 2) ? s0[2 * i] : s0[2 * i + 1];
        float keep = (c & 2) ? s0[2 * i + 1] : s0[2 * i];
        s1[i] = keep + __shfl_xor(send, 2);
    }
    float s2[2];
    #pragma unroll
    for (int i = 0; i < 2; ++i) {
        float send = (c & 4) ? s1[2 * i] : s1[2 * i + 1];
        float keep = (c & 4) ? s1[2 * i + 1] : s1[2 * i];
        s2[i] = keep + __shfl_xor(send, 4);
    }
    float send3 = (c & 8) ? s2[0] : s2[1];
    float keep3 = (c & 8) ? s2[1] : s2[0];
    float s3 = keep3 + __shfl_xor(send3, 8);    // full c-sum for j=c
    int m = (c >> 2) * 16 + q * 4 + (c & 3);
    lds3[m * 6 + w] = s3;
    __syncthreads();   // B2: lds3 ready

    if (tid < 64) {
        const float* pm = lds3 + tid * 6;
        out[r0 + tid] = pm[0] + pm[1] + pm[2] + pm[3] + b3v;
    }
}

extern "C" void kernel_launch(void* const* d_in, const int* in_sizes, int n_in,
                              void* d_out, int out_size, void* d_ws, size_t ws_size,
                              hipStream_t stream) {
    const float* state = (const float*)d_in[0];
    const float* afeat = (const float*)d_in[1];
    const float* W1    = (const float*)d_in[2];
    const float* b1    = (const float*)d_in[3];
    const float* W2    = (const float*)d_in[4];
    const float* b2    = (const float*)d_in[5];
    const float* W3    = (const float*)d_in[6];
    const float* b3    = (const float*)d_in[7];
    float* out = (float*)d_out;

    // ws: hstate 256KB | pw1at 32KB (16384 f16) | pw2 64KB (32768 f16)
    float* hstate = (float*)d_ws;
    f16* pw1at = (f16*)((char*)d_ws + 65536 * sizeof(float));
    f16* pw2   = pw1at + 16384;

    prep_kernel<<<280, 256, 0, stream>>>(W1, W2, state, b1, pw1at, pw2, hstate);
    fused_kernel<<<4000, 256, 0, stream>>>(afeat, hstate, pw1at, pw2, b2, W3, b3, out);
}

// Round 3
// 133.567 us; speedup vs baseline: 1.0568x; 1.0259x over previous
//
#include <hip/hip_runtime.h>

typedef _Float16 f16;
typedef f16 f16x4 __attribute__((ext_vector_type(4)));
typedef f16 f16x8 __attribute__((ext_vector_type(8)));
typedef float f32x4 __attribute__((ext_vector_type(4)));

// state_embed (256,512) f32 | action_feats (256,1000,64) f32 | W1 (576,256) | b1 (256)
// W2 (256,128) | b2 (128) | W3 (128,1) | b3 (1)  -> out (256,1000) f32

#define AF_STRIDE 64    // unpadded; XOR swizzle supplies the bank rotation
#define H1_STRIDE 256   // unpadded; XOR swizzle supplies the bank rotation

// ---------- prep: pack W1a^T (A-frag), W2 (B-frag), compute h_state ----------
// A-frag (16x16x32): lane L holds A[m=L&15][k=(L>>4)*8+j], j=0..7
// B-frag:            lane L holds B[k=(L>>4)*8+j][n=L&15]
__global__ __launch_bounds__(256) void prep_kernel(const float* __restrict__ W1,
                                                   const float* __restrict__ W2,
                                                   const float* __restrict__ state,
                                                   const float* __restrict__ b1,
                                                   f16* __restrict__ pw1at,
                                                   f16* __restrict__ pw2,
                                                   float* __restrict__ hstate) {
    __shared__ float srow[512];
    int blk = blockIdx.x;
    int tid = threadIdx.x;
    if (blk < 24) {
        int idx = blk * 256 + tid;              // 0..6143
        int F = idx >> 6;                       // fragment id 0..95
        int L = idx & 63;
        int q = L >> 4, c = L & 15;
        f16x8 v;
        if (F < 32) {                           // pw1at: M=256h (mt 0..15), K=64f (kt 0..1)
            int mt = F >> 1, kt = F & 1;
            #pragma unroll
            for (int j = 0; j < 8; ++j) {
                int f = kt * 32 + q * 8 + j;
                v[j] = (f16)W1[(size_t)(512 + f) * 256 + mt * 16 + c];
            }
            *(f16x8*)(pw1at + ((size_t)F * 64 + L) * 8) = v;
        } else {                                // pw2: K=256 (kt 0..7), N=128 (nt 0..7)
            int F2 = F - 32;
            int nt = F2 >> 3, kt = F2 & 7;
            #pragma unroll
            for (int j = 0; j < 8; ++j) {
                int k = kt * 32 + q * 8 + j;
                v[j] = (f16)W2[(size_t)k * 128 + nt * 16 + c];
            }
            *(f16x8*)(pw2 + ((size_t)F2 * 64 + L) * 8) = v;
        }
    } else {
        int b = blk - 24;                       // one batch row per block (fp32 exact)
        srow[tid] = state[(size_t)b * 512 + tid];
        srow[tid + 256] = state[(size_t)b * 512 + 256 + tid];
        __syncthreads();
        float a0 = 0.f, a1 = 0.f;
        #pragma unroll 16
        for (int f = 0; f < 512; f += 2) {
            a0 = fmaf(srow[f],     W1[(size_t)f * 256 + tid],       a0);
            a1 = fmaf(srow[f + 1], W1[(size_t)(f + 1) * 256 + tid], a1);
        }
        hstate[(size_t)b * 256 + tid] = a0 + a1 + b1[tid];
    }
}

// ---------- fused MLP: 1 tile x 64 actions/block, h-split waves ----------
// History: R9 1-tile 40960B -> 4 blk/CU, Occ 33%, fused 40.8us — but VGPR fell to 64:
//   zero pipelining; per-wave time dominated by exposed L2 latency (hstate loads in
//   GEMM1 epilogue, pw2 loads in GEMM2 kt-loop). Regs 64..128 are free (LDS caps 4/CU).
// R10 (this): spend registers on ILP + cut epilogue VALU.
//   (a) hoist 8 hstate f32x4 loads above B0 (+32 regs, hides ~800cy).
//   (b) depth-2 pw2 prefetch in GEMM2 (+16 regs).
//   (c) operand-swapped GEMM2: mfma(A=pw2frag, B=a2frag) -> D[m=g][n=action].
//       pw2's B-frag [k=h][n=g] is bit-identical to A-frag of W2^T; a2[rb] is
//       bit-identical to B-frag of h1^T. Action lands in-lane (col=c) so the
//       15-stage butterfly + 60 cndmask collapses to 2 shfl_xor (q-reduce) +
//       the small lds3 cross-wave combine. -80 VALU, -25 transient regs.
__global__ __launch_bounds__(256, 4) void fused_kernel(const float* __restrict__ afeat,
                                                       const float* __restrict__ hstate,
                                                       const f16* __restrict__ pw1at,
                                                       const f16* __restrict__ pw2,
                                                       const float* __restrict__ b2,
                                                       const float* __restrict__ W3,
                                                       const float* __restrict__ b3,
                                                       float* __restrict__ out) {
    __shared__ __align__(16) char smem[(64 * AF_STRIDE + 64 * H1_STRIDE) * 2];  // 40960 B
    f16* afs = (f16*)smem;                                 // 64 rows x 64 f16, swizzled
    f16* h1s = (f16*)(smem + 64 * AF_STRIDE * 2);          // 64 rows x 256 f16, swizzled
    float* lds3 = (float*)smem;                            // aliases afs rows 0..11

    int tid = threadIdx.x;
    int w = tid >> 6;                 // wave 0..3
    int L = tid & 63;
    int q = L >> 4, c = L & 15;
    int r0 = blockIdx.x * 64;         // first global action row of this block's tile

    // ---- resident W1a^T A-frags (32 VGPRs), wave's h-slice [64w, 64w+64) ----
    f16x8 a1f[4][2];
    #pragma unroll
    for (int i = 0; i < 4; ++i)
        #pragma unroll
        for (int kt = 0; kt < 2; ++kt)
            a1f[i][kt] = *(const f16x8*)(pw1at + ((size_t)((4 * w + i) * 2 + kt) * 64 + L) * 8);

    // ---- stage tile: 64 rows x 64 f32 -> f16 LDS (swizzled) ----
    #pragma unroll
    for (int i = 0; i < 2; ++i) {
        int id = i * 256 + tid;               // 32B-chunk id 0..511
        int row = id >> 3, c32 = id & 7;
        const float* p = afeat + (size_t)(r0 + row) * 64 + c32 * 8;
        f32x4 lo = *(const f32x4*)p;
        f32x4 hi = *(const f32x4*)(p + 4);
        f16x8 v;
        v[0] = (f16)lo[0]; v[1] = (f16)lo[1]; v[2] = (f16)lo[2]; v[3] = (f16)lo[3];
        v[4] = (f16)hi[0]; v[5] = (f16)hi[1]; v[6] = (f16)hi[2]; v[7] = (f16)hi[3];
        *(f16x8*)(afs + row * AF_STRIDE + ((c32 * 8) ^ ((row & 7) << 3))) = v;
    }

    int b0i = r0 / 1000;
    int boundary = (b0i + 1) * 1000;
    int b1i = b0i < 255 ? b0i + 1 : 255;

    // ---- (a) hoist hstate loads: both candidate batch rows, wave's h-slice ----
    f32x4 hsva[4], hsvb[4];
    #pragma unroll
    for (int i = 0; i < 4; ++i) {
        int hbase = (4 * w + i) * 16 + q * 4;
        hsva[i] = *(const f32x4*)(hstate + (size_t)b0i * 256 + hbase);
        hsvb[i] = *(const f32x4*)(hstate + (size_t)b1i * 256 + hbase);
    }

    float b3v = b3[0];
    __syncthreads();   // B0: afs staged

    int sx = (c & 7) << 3;            // lane's row-class XOR (rows used below are X*16+c)

    // ---- GEMM1 B-frags (shared across i-slices) ----
    f16x8 bf[4][2];
    #pragma unroll
    for (int nt = 0; nt < 4; ++nt)
        #pragma unroll
        for (int kt = 0; kt < 2; ++kt)
            bf[nt][kt] = *(const f16x8*)(afs + (nt * 16 + c) * AF_STRIDE + ((kt * 32 + q * 8) ^ sx));

    // ---- GEMM1 interleaved with epilogue-1: acc live = 16 regs per i-slice ----
    #pragma unroll
    for (int i = 0; i < 4; ++i) {
        f32x4 acc[4];
        #pragma unroll
        for (int nt = 0; nt < 4; ++nt) {
            acc[nt] = (f32x4){0.f, 0.f, 0.f, 0.f};
            #pragma unroll
            for (int kt = 0; kt < 2; ++kt)
                acc[nt] = __builtin_amdgcn_mfma_f32_16x16x32_f16(
                    a1f[i][kt], bf[nt][kt], acc[nt], 0, 0, 0);
        }
        int hbase = (4 * w + i) * 16 + q * 4;
        #pragma unroll
        for (int nt = 0; nt < 4; ++nt) {
            bool sel = (r0 + nt * 16 + c) >= boundary;
            f16x4 hv;
            #pragma unroll
            for (int reg = 0; reg < 4; ++reg) {
                float v = acc[nt][reg] + (sel ? hsvb[i][reg] : hsva[i][reg]);
                v = v > 0.f ? v : 0.f;
                hv[reg] = (f16)v;
            }
            *(f16x4*)(h1s + (nt * 16 + c) * H1_STRIDE + (hbase ^ sx)) = hv;
        }
    }
    __syncthreads();   // B1: h1s ready; afs reads done -> lds3 region writable

    // ---- GEMM2 (swapped): D[m=g][n=action] = W2^T @ h1^T, wave owns gt=2w,2w+1 ----
    // b2/W3 vectors for this lane's g rows: g = (2w+gti)*16 + 4q + reg
    f32x4 b2v[2], w3v[2];
    #pragma unroll
    for (int gti = 0; gti < 2; ++gti) {
        int gb = (2 * w + gti) * 16 + q * 4;
        b2v[gti] = *(const f32x4*)(b2 + gb);
        w3v[gti] = *(const f32x4*)(W3 + gb);
    }

    f32x4 acc2[4][2];
    #pragma unroll
    for (int rb = 0; rb < 4; ++rb) {
        acc2[rb][0] = (f32x4){0.f, 0.f, 0.f, 0.f};
        acc2[rb][1] = (f32x4){0.f, 0.f, 0.f, 0.f};
    }

    // (b) depth-2 explicit prefetch of pw2 frag pairs
    f16x8 pwf[2][2];
    #pragma unroll
    for (int gti = 0; gti < 2; ++gti)
        pwf[0][gti] = *(const f16x8*)(pw2 + ((size_t)((2 * w + gti) * 8 + 0) * 64 + L) * 8);

    #pragma unroll
    for (int kt = 0; kt < 8; ++kt) {
        if (kt < 7) {
            #pragma unroll
            for (int gti = 0; gti < 2; ++gti)
                pwf[(kt + 1) & 1][gti] =
                    *(const f16x8*)(pw2 + ((size_t)((2 * w + gti) * 8 + kt + 1) * 64 + L) * 8);
        }
        f16x8 a2[4];
        #pragma unroll
        for (int rb = 0; rb < 4; ++rb)
            a2[rb] = *(const f16x8*)(h1s + (rb * 16 + c) * H1_STRIDE + ((kt * 32 + q * 8) ^ sx));
        #pragma unroll
        for (int gti = 0; gti < 2; ++gti)
            #pragma unroll
            for (int rb = 0; rb < 4; ++rb)
                acc2[rb][gti] = __builtin_amdgcn_mfma_f32_16x16x32_f16(
                    pwf[kt & 1][gti], a2[rb], acc2[rb][gti], 0, 0, 0);
    }

    // ---- layer 3: in-lane relu+dot over this wave's 32 g; reduce over q then waves ----
    float pa[4];
    #pragma unroll
    for (int rb = 0; rb < 4; ++rb) {
        float s = 0.f;
        #pragma unroll
        for (int gti = 0; gti < 2; ++gti)
            #pragma unroll
            for (int reg = 0; reg < 4; ++reg) {
                float v = acc2[rb][gti][reg] + b2v[gti][reg];
                v = v > 0.f ? v : 0.f;
                s = fmaf(v, w3v[gti][reg], s);
            }
        pa[rb] = s;
    }
    #pragma unroll
    for (int rb = 0; rb < 4; ++rb) {
        pa[rb] += __shfl_xor(pa[rb], 16);
        pa[rb] += __shfl_xor(pa[rb], 32);
    }
    if (L < 16) {
        #pragma unroll
        for (int rb = 0; rb < 4; ++rb)
            lds3[(rb * 16 + L) * 6 + w] = pa[rb];
    }
    __syncthreads();   // B2: lds3 ready

    if (tid < 64) {
        const float* pm = lds3 + tid * 6;
        out[r0 + tid] = pm[0] + pm[1] + pm[2] + pm[3] + b3v;
    }
}

extern "C" void kernel_launch(void* const* d_in, const int* in_sizes, int n_in,
                              void* d_out, int out_size, void* d_ws, size_t ws_size,
                              hipStream_t stream) {
    const float* state = (const float*)d_in[0];
    const float* afeat = (const float*)d_in[1];
    const float* W1    = (const float*)d_in[2];
    const float* b1    = (const float*)d_in[3];
    const float* W2    = (const float*)d_in[4];
    const float* b2    = (const float*)d_in[5];
    const float* W3    = (const float*)d_in[6];
    const float* b3    = (const float*)d_in[7];
    float* out = (float*)d_out;

    // ws: hstate 256KB | pw1at 32KB (16384 f16) | pw2 64KB (32768 f16)
    float* hstate = (float*)d_ws;
    f16* pw1at = (f16*)((char*)d_ws + 65536 * sizeof(float));
    f16* pw2   = pw1at + 16384;

    prep_kernel<<<280, 256, 0, stream>>>(W1, W2, state, b1, pw1at, pw2, hstate);
    fused_kernel<<<4000, 256, 0, stream>>>(afeat, hstate, pw1at, pw2, b2, W3, b3, out);
}

// Round 5
// 133.014 us; speedup vs baseline: 1.0612x; 1.0042x over previous
//
#include <hip/hip_runtime.h>

typedef _Float16 f16;
typedef f16 f16x4 __attribute__((ext_vector_type(4)));
typedef f16 f16x8 __attribute__((ext_vector_type(8)));
typedef float f32x4 __attribute__((ext_vector_type(4)));

// state_embed (256,512) f32 | action_feats (256,1000,64) f32 | W1 (576,256) | b1 (256)
// W2 (256,128) | b2 (128) | W3 (128,1) | b3 (1)  -> out (256,1000) f32

#define AF_STRIDE 64    // unpadded; XOR swizzle supplies the bank rotation
#define H1_STRIDE 256   // unpadded; XOR swizzle supplies the bank rotation

// ---------- prep: pack W1a^T (A-frag), W2 (B-frag), compute h_state ----------
// A-frag (16x16x32): lane L holds A[m=L&15][k=(L>>4)*8+j], j=0..7
// B-frag:            lane L holds B[k=(L>>4)*8+j][n=L&15]
__global__ __launch_bounds__(256) void prep_kernel(const float* __restrict__ W1,
                                                   const float* __restrict__ W2,
                                                   const float* __restrict__ state,
                                                   const float* __restrict__ b1,
                                                   f16* __restrict__ pw1at,
                                                   f16* __restrict__ pw2,
                                                   float* __restrict__ hstate) {
    __shared__ float srow[512];
    int blk = blockIdx.x;
    int tid = threadIdx.x;
    if (blk < 24) {
        int idx = blk * 256 + tid;              // 0..6143
        int F = idx >> 6;                       // fragment id 0..95
        int L = idx & 63;
        int q = L >> 4, c = L & 15;
        f16x8 v;
        if (F < 32) {                           // pw1at: M=256h (mt 0..15), K=64f (kt 0..1)
            int mt = F >> 1, kt = F & 1;
            #pragma unroll
            for (int j = 0; j < 8; ++j) {
                int f = kt * 32 + q * 8 + j;
                v[j] = (f16)W1[(size_t)(512 + f) * 256 + mt * 16 + c];
            }
            *(f16x8*)(pw1at + ((size_t)F * 64 + L) * 8) = v;
        } else {                                // pw2: K=256 (kt 0..7), N=128 (nt 0..7)
            int F2 = F - 32;
            int nt = F2 >> 3, kt = F2 & 7;
            #pragma unroll
            for (int j = 0; j < 8; ++j) {
                int k = kt * 32 + q * 8 + j;
                v[j] = (f16)W2[(size_t)k * 128 + nt * 16 + c];
            }
            *(f16x8*)(pw2 + ((size_t)F2 * 64 + L) * 8) = v;
        }
    } else {
        int b = blk - 24;                       // one batch row per block (fp32 exact)
        srow[tid] = state[(size_t)b * 512 + tid];
        srow[tid + 256] = state[(size_t)b * 512 + 256 + tid];
        __syncthreads();
        float a0 = 0.f, a1 = 0.f;
        #pragma unroll 16
        for (int f = 0; f < 512; f += 2) {
            a0 = fmaf(srow[f],     W1[(size_t)f * 256 + tid],       a0);
            a1 = fmaf(srow[f + 1], W1[(size_t)(f + 1) * 256 + tid], a1);
        }
        hstate[(size_t)b * 256 + tid] = a0 + a1 + b1[tid];
    }
}

// ---------- fused MLP: 1 tile x 64 actions/block, h-split waves ----------
// History: R9 4 blk/CU Occ 33% fused 40.8us, VALUBusy 37% > MfmaUtil 24% — VALU-heavy.
// R10: hoisted hstate, swapped GEMM2 (butterfly -> 2 shfl), pw2 depth-2 -> fused <41.
// R11/R12 (this; R11 bench was a container-infra failure, kernel unchanged):
//   (a) hstate folded into MFMA C-init (acc = sel?hsvb:hsva) — saves 64 v_add/thread.
//   (b) relu in packed f16 (v_pk_max_f16 after cvt; monotone cvt => same result).
//   (c) swizzled LDS addrs decomposed to 2 base pointers (bo, bo^64) + ds offset
//       immediates: 2*((kt*32+q*8)^sx) == (kt>>1)*128 + (bo ^ ((kt&1)*64)). Zero
//       per-access VALU for bf reads, a2 reads, h1 writes (per-i base).
//   (d) depth-2 double-buffer on a2 LDS reads (mirrors pw2 prefetch).
//   (e) s_setprio(1) around GEMM2 MFMA clusters (blocks phase-independent on a CU).
//   (f) b2/W3/b3 loads deferred past B1 (GEMM1 live regs <=~120, keeps 4 blk/CU).
__global__ __launch_bounds__(256, 4) void fused_kernel(const float* __restrict__ afeat,
                                                       const float* __restrict__ hstate,
                                                       const f16* __restrict__ pw1at,
                                                       const f16* __restrict__ pw2,
                                                       const float* __restrict__ b2,
                                                       const float* __restrict__ W3,
                                                       const float* __restrict__ b3,
                                                       float* __restrict__ out) {
    __shared__ __align__(16) char smem[(64 * AF_STRIDE + 64 * H1_STRIDE) * 2];  // 40960 B
    f16* afs = (f16*)smem;                                 // 64 rows x 64 f16, swizzled
    f16* h1s = (f16*)(smem + 64 * AF_STRIDE * 2);          // 64 rows x 256 f16, swizzled
    float* lds3 = (float*)smem;                            // aliases afs rows 0..11

    int tid = threadIdx.x;
    int w = tid >> 6;                 // wave 0..3
    int L = tid & 63;
    int q = L >> 4, c = L & 15;
    int r0 = blockIdx.x * 64;         // first global action row of this block's tile

    // ---- issue HBM stage loads FIRST (longest latency) ----
    f32x4 sl[2][2];
    #pragma unroll
    for (int i = 0; i < 2; ++i) {
        int id = i * 256 + tid;               // 32B-chunk id 0..511
        int row = id >> 3, c32 = id & 7;
        const float* p = afeat + (size_t)(r0 + row) * 64 + c32 * 8;
        sl[i][0] = *(const f32x4*)p;
        sl[i][1] = *(const f32x4*)(p + 4);
    }

    // ---- L2 loads: resident W1a^T A-frags (32 VGPRs), wave's h-slice [64w,64w+64) ----
    f16x8 a1f[4][2];
    #pragma unroll
    for (int i = 0; i < 4; ++i)
        #pragma unroll
        for (int kt = 0; kt < 2; ++kt)
            a1f[i][kt] = *(const f16x8*)(pw1at + ((size_t)((4 * w + i) * 2 + kt) * 64 + L) * 8);

    int b0i = r0 / 1000;
    int boundary = (b0i + 1) * 1000;
    int b1i = b0i < 255 ? b0i + 1 : 255;

    // ---- hoisted hstate: both candidate batch rows, wave's h-slice ----
    f32x4 hsva[4], hsvb[4];
    #pragma unroll
    for (int i = 0; i < 4; ++i) {
        int hbase = (4 * w + i) * 16 + q * 4;
        hsva[i] = *(const f32x4*)(hstate + (size_t)b0i * 256 + hbase);
        hsvb[i] = *(const f32x4*)(hstate + (size_t)b1i * 256 + hbase);
    }

    // ---- convert + write afs (consumes sl) ----
    #pragma unroll
    for (int i = 0; i < 2; ++i) {
        int id = i * 256 + tid;
        int row = id >> 3, c32 = id & 7;
        f16x8 v;
        v[0] = (f16)sl[i][0][0]; v[1] = (f16)sl[i][0][1];
        v[2] = (f16)sl[i][0][2]; v[3] = (f16)sl[i][0][3];
        v[4] = (f16)sl[i][1][0]; v[5] = (f16)sl[i][1][1];
        v[6] = (f16)sl[i][1][2]; v[7] = (f16)sl[i][1][3];
        *(f16x8*)(afs + row * AF_STRIDE + ((c32 * 8) ^ ((row & 7) << 3))) = v;
    }
    __syncthreads();   // B0: afs staged

    int sx = (c & 7) << 3;            // lane's row-class XOR in f16 units (rows are X*16+c)
    unsigned bo = ((q * 8) ^ sx) * 2; // byte offset inside 64-f16 swizzle class, kt-even

    // ---- GEMM1 B-frags via base+imm: byte = c*128 + nt*2048 + (bo ^ (kt*64)) ----
    const char* Bp0 = (const char*)afs + c * 128 + bo;
    const char* Bp1 = (const char*)afs + c * 128 + (bo ^ 64);
    f16x8 bf[4][2];
    #pragma unroll
    for (int nt = 0; nt < 4; ++nt) {
        bf[nt][0] = *(const f16x8*)(Bp0 + nt * 2048);
        bf[nt][1] = *(const f16x8*)(Bp1 + nt * 2048);
    }

    // ---- GEMM1, hstate folded into C-init; relu in packed f16 ----
    const f16x4 zf = {(f16)0.f, (f16)0.f, (f16)0.f, (f16)0.f};
    #pragma unroll
    for (int i = 0; i < 4; ++i) {
        f32x4 acc[4];
        #pragma unroll
        for (int nt = 0; nt < 4; ++nt) {
            bool sel = (r0 + nt * 16 + c) >= boundary;
            acc[nt] = sel ? hsvb[i] : hsva[i];
            #pragma unroll
            for (int kt = 0; kt < 2; ++kt)
                acc[nt] = __builtin_amdgcn_mfma_f32_16x16x32_f16(
                    a1f[i][kt], bf[nt][kt], acc[nt], 0, 0, 0);
        }
        // h1 write: byte = c*512 + nt*8192 + 2*((((4w+i)*16+q*4) ^ sx))
        char* wp = (char*)h1s + c * 512 + ((((4 * w + i) * 16 + q * 4) ^ sx) * 2);
        #pragma unroll
        for (int nt = 0; nt < 4; ++nt) {
            f16x4 hv;
            hv[0] = (f16)acc[nt][0]; hv[1] = (f16)acc[nt][1];
            hv[2] = (f16)acc[nt][2]; hv[3] = (f16)acc[nt][3];
            hv = __builtin_elementwise_max(hv, zf);
            *(f16x4*)(wp + nt * 8192) = hv;
        }
    }
    __syncthreads();   // B1: h1s ready; afs reads done -> lds3 region writable

    // ---- GEMM2 (swapped): D[m=g][n=action], wave owns gt=2w,2w+1; depth-2 on both ops ----
    f32x4 b2v[2], w3v[2];
    #pragma unroll
    for (int gti = 0; gti < 2; ++gti) {
        int gb = (2 * w + gti) * 16 + q * 4;
        b2v[gti] = *(const f32x4*)(b2 + gb);
        w3v[gti] = *(const f32x4*)(W3 + gb);
    }
    float b3v = b3[0];

    // a2 read: byte = c*512 + rb*8192 + (kt>>1)*128 + (bo ^ ((kt&1)*64))
    const char* Ap0 = (const char*)h1s + c * 512 + bo;
    const char* Ap1 = (const char*)h1s + c * 512 + (bo ^ 64);

    f32x4 acc2[4][2];
    #pragma unroll
    for (int rb = 0; rb < 4; ++rb) {
        acc2[rb][0] = (f32x4){0.f, 0.f, 0.f, 0.f};
        acc2[rb][1] = (f32x4){0.f, 0.f, 0.f, 0.f};
    }

    f16x8 a2[2][4], pwf[2][2];
    #pragma unroll
    for (int rb = 0; rb < 4; ++rb)
        a2[0][rb] = *(const f16x8*)(Ap0 + rb * 8192);
    #pragma unroll
    for (int gti = 0; gti < 2; ++gti)
        pwf[0][gti] = *(const f16x8*)(pw2 + ((size_t)((2 * w + gti) * 8) * 64 + L) * 8);

    #pragma unroll
    for (int kt = 0; kt < 8; ++kt) {
        if (kt < 7) {
            const char* Apn = ((kt + 1) & 1) ? Ap1 : Ap0;
            #pragma unroll
            for (int rb = 0; rb < 4; ++rb)
                a2[(kt + 1) & 1][rb] =
                    *(const f16x8*)(Apn + ((kt + 1) >> 1) * 128 + rb * 8192);
            #pragma unroll
            for (int gti = 0; gti < 2; ++gti)
                pwf[(kt + 1) & 1][gti] =
                    *(const f16x8*)(pw2 + ((size_t)((2 * w + gti) * 8 + kt + 1) * 64 + L) * 8);
        }
        __builtin_amdgcn_s_setprio(1);
        #pragma unroll
        for (int gti = 0; gti < 2; ++gti)
            #pragma unroll
            for (int rb = 0; rb < 4; ++rb)
                acc2[rb][gti] = __builtin_amdgcn_mfma_f32_16x16x32_f16(
                    pwf[kt & 1][gti], a2[kt & 1][rb], acc2[rb][gti], 0, 0, 0);
        __builtin_amdgcn_s_setprio(0);
    }

    // ---- layer 3: in-lane relu+dot over this wave's 32 g; reduce over q then waves ----
    float pa[4];
    #pragma unroll
    for (int rb = 0; rb < 4; ++rb) {
        float s = 0.f;
        #pragma unroll
        for (int gti = 0; gti < 2; ++gti)
            #pragma unroll
            for (int reg = 0; reg < 4; ++reg) {
                float v = acc2[rb][gti][reg] + b2v[gti][reg];
                v = v > 0.f ? v : 0.f;
                s = fmaf(v, w3v[gti][reg], s);
            }
        pa[rb] = s;
    }
    #pragma unroll
    for (int rb = 0; rb < 4; ++rb) {
        pa[rb] += __shfl_xor(pa[rb], 16);
        pa[rb] += __shfl_xor(pa[rb], 32);
    }
    if (L < 16) {
        #pragma unroll
        for (int rb = 0; rb < 4; ++rb)
            lds3[(rb * 16 + L) * 6 + w] = pa[rb];
    }
    __syncthreads();   // B2: lds3 ready

    if (tid < 64) {
        const float* pm = lds3 + tid * 6;
        out[r0 + tid] = pm[0] + pm[1] + pm[2] + pm[3] + b3v;
    }
}

extern "C" void kernel_launch(void* const* d_in, const int* in_sizes, int n_in,
                              void* d_out, int out_size, void* d_ws, size_t ws_size,
                              hipStream_t stream) {
    const float* state = (const float*)d_in[0];
    const float* afeat = (const float*)d_in[1];
    const float* W1    = (const float*)d_in[2];
    const float* b1    = (const float*)d_in[3];
    const float* W2    = (const float*)d_in[4];
    const float* b2    = (const float*)d_in[5];
    const float* W3    = (const float*)d_in[6];
    const float* b3    = (const float*)d_in[7];
    float* out = (float*)d_out;

    // ws: hstate 256KB | pw1at 32KB (16384 f16) | pw2 64KB (32768 f16)
    float* hstate = (float*)d_ws;
    f16* pw1at = (f16*)((char*)d_ws + 65536 * sizeof(float));
    f16* pw2   = pw1at + 16384;

    prep_kernel<<<280, 256, 0, stream>>>(W1, W2, state, b1, pw1at, pw2, hstate);
    fused_kernel<<<4000, 256, 0, stream>>>(afeat, hstate, pw1at, pw2, b2, W3, b3, out);
}